// Round 22
// baseline (193.370 us; speedup 1.0000x reference)
//
#include <hip/hip_runtime.h>
#include <math.h>

#define B_    32
#define C_    384
#define RHO_  25
#define WP_   256
#define PIX_  4096
#define D_    768
#define HID_  40
#define NROWS (B_*C_*RHO_)     // 307200
#define FE_N (RHO_*B_*D_)      // 614400
#define PCH 8                  // p-chunks of 512 for cart
#define WFRAG_B 262144         // per-b Wfrag halves: 128 tsteps x 4 slots x 64 lanes x 8
#define PNW 8192               // polar waves (2048 blocks x 4)

typedef _Float16 half_t;
typedef __attribute__((ext_vector_type(8))) _Float16 half8;
typedef __attribute__((ext_vector_type(4))) float f32x4;

__device__ __forceinline__ float gelu_exact(float x) {
    return 0.5f * x * (1.f + erff(x * 0.70710678118654752f));
}

// ---------------- K1: prep — bins(->MFMA-fragment f16 hi/lo) + W1T + fe-zero ----------------
// Must precede main_kernel (produces Wfrag that cart role consumes).
__global__ __launch_bounds__(256) void prep_kernel(const float* __restrict__ grid,
        const float* __restrict__ W1_0, const float* __restrict__ W1s,
        half_t* __restrict__ Wfrag, float* __restrict__ W1T, float* __restrict__ fe) {
    __shared__ float lb[PIX_];
    int tid = threadIdx.x;
    int bid = blockIdx.x;
    if (bid < B_ * RHO_) {
        // -------- bins role: LDS scatter, then write f16 hi/lo in MFMA fragment order --------
        for (int i = tid; i < PIX_ / 4; i += 256) ((float4*)lb)[i] = make_float4(0.f, 0.f, 0.f, 0.f);
        __syncthreads();
        int pt = bid * WP_ + tid;
        float2 g = ((const float2*)grid)[pt];
        float ix = (g.x + 1.f) * 32.f - 0.5f;
        float iy = (g.y + 1.f) * 32.f - 0.5f;
        float x0f = floorf(ix), y0f = floorf(iy);
        float fx = ix - x0f, fy = iy - y0f;
        int x0 = (int)x0f, y0 = (int)y0f;
        const float s = 1.f / 256.f;
        if ((unsigned)x0 < 64u) {
            if ((unsigned)y0 < 64u)       atomicAdd(&lb[y0 * 64 + x0],       (1.f - fx) * (1.f - fy) * s);
            if ((unsigned)(y0 + 1) < 64u) atomicAdd(&lb[(y0 + 1) * 64 + x0], (1.f - fx) * fy * s);
        }
        if ((unsigned)(x0 + 1) < 64u) {
            if ((unsigned)y0 < 64u)       atomicAdd(&lb[y0 * 64 + x0 + 1],       fx * (1.f - fy) * s);
            if ((unsigned)(y0 + 1) < 64u) atomicAdd(&lb[(y0 + 1) * 64 + x0 + 1], fx * fy * s);
        }
        __syncthreads();
        int b = bid / RHO_, rho = bid % RHO_;
        int slot_h = (rho < 16) ? 0 : 1;                 // hi slot; lo slot = slot_h + 2
        int r16 = rho & 15;
        half_t* base = Wfrag + (size_t)b * WFRAG_B;
        for (int i = tid; i < PIX_; i += 256) {
            int t = i >> 5, k = i & 31;
            int kg = k >> 3, ii = k & 7;
            float wv = lb[i];
            half_t h = (half_t)wv;
            size_t idx = ((size_t)(t * 4 + slot_h) * 64 + kg * 16 + r16) * 8 + ii;
            base[idx] = h;                               // hi
            base[idx + 1024] = (half_t)(wv - (float)h);  // lo
        }
    } else if (bid < B_ * RHO_ + 25) {
        // -------- W1T role --------
        int i = bid - B_ * RHO_;                         // head 0..24
        const float* src = (i == 0) ? W1_0 : (W1s + (size_t)(i - 1) * 769 * HID_);
        float* dst = W1T + (size_t)i * HID_ * D_;
        for (int idx = tid; idx < HID_ * D_; idx += 256) {
            int j = idx / D_, c = idx % D_;
            dst[idx] = src[c * HID_ + j];
        }
    } else {
        // -------- fe-zero role: cart half only, 16 rows per block --------
        int z = bid - (B_ * RHO_ + 25);                  // 0..49
        for (int i = tid; i < 16 * 96; i += 256) {       // 16 rows x 96 float4
            int row = z * 16 + (i / 96), e = i % 96;
            ((float4*)fe)[(size_t)row * 192 + 96 + e] = make_float4(0.f, 0.f, 0.f, 0.f);
        }
    }
}

// ---------------- K2: main — octet-interleaved polar mean + cart MFMA GEMM ----------------
// 448 octets (3584 blocks): per 7-octet group, 3 cart + 4 polar -> both roles on all XCDs.
// Cart role: byte-identical R21 (wave-synchronous, no block barriers in main loop).
// Polar role: grid-stride ILP-4 width-mean; its HBM stream fills cart's latency stalls.
__global__ __launch_bounds__(256) void main_kernel(const float* __restrict__ polar,
        const float* __restrict__ cart, const half_t* __restrict__ Wfrag,
        float* __restrict__ fe) {
    __shared__ float smem[8704];                         // cart: 4 waves x 2 bufs x [16][68]
    int tid = threadIdx.x;
    int o = blockIdx.x >> 3, sub = blockIdx.x & 7;
    int g = o / 7, r = o % 7;
    int w = tid >> 6, lane = tid & 63;

    if (r < 3) {
        // -------- cart role (R21 body) --------
        int bid = (g * 3 + r) * 8 + sub;                 // 0..1535
        int b  = bid / (6 * PCH);
        int ct = (bid / PCH) % 6;
        int pc = bid % PCH;
        int row16 = lane & 15, kg = lane >> 4;

        const float* xgbase = cart + ((size_t)b * C_ + ct * 64 + w * 16) * PIX_ + pc * 512;
        const half_t* wbase = Wfrag + (size_t)b * WFRAG_B + (size_t)(pc * 16) * 2048 + lane * 8;

        float* xl = smem + w * 2176;
        int srow = lane >> 4;
        int scol = (lane & 15) * 4;

        f32x4 acc0 = {0.f, 0.f, 0.f, 0.f};
        f32x4 acc1 = {0.f, 0.f, 0.f, 0.f};
        float4 sreg[4];
        half8 wf[2][8];

        #pragma unroll
        for (int i = 0; i < 4; ++i)
            sreg[i] = *(const float4*)(xgbase + (size_t)(srow + 4 * i) * PIX_ + scol);
        #pragma unroll
        for (int ks = 0; ks < 2; ++ks)
            #pragma unroll
            for (int s = 0; s < 4; ++s)
                wf[0][ks * 4 + s] = *(const half8*)(wbase + (size_t)(ks * 4 + s) * 512);
        #pragma unroll
        for (int i = 0; i < 4; ++i)
            *(float4*)(&xl[(srow + 4 * i) * 68 + scol]) = sreg[i];
        #pragma unroll
        for (int i = 0; i < 4; ++i)
            sreg[i] = *(const float4*)(xgbase + (size_t)(srow + 4 * i) * PIX_ + 64 + scol);
        #pragma unroll
        for (int ks = 0; ks < 2; ++ks)
            #pragma unroll
            for (int s = 0; s < 4; ++s)
                wf[1][ks * 4 + s] = *(const half8*)(wbase + (size_t)((2 + ks) * 4 + s) * 512);

        #pragma unroll
        for (int t = 0; t < 8; ++t) {
            const int cb = t & 1;
            const float* xb = xl + cb * 1088;
            #pragma unroll
            for (int ks = 0; ks < 2; ++ks) {
                float4 xa = *(const float4*)(xb + row16 * 68 + ks * 32 + kg * 8);
                float4 xc = *(const float4*)(xb + row16 * 68 + ks * 32 + kg * 8 + 4);
                float xs[8] = {xa.x, xa.y, xa.z, xa.w, xc.x, xc.y, xc.z, xc.w};
                half8 ah, al;
                #pragma unroll
                for (int i = 0; i < 8; ++i) {
                    half_t h = (half_t)xs[i];
                    ah[i] = h;
                    al[i] = (half_t)(xs[i] - (float)h);
                }
                acc0 = __builtin_amdgcn_mfma_f32_16x16x32_f16(ah, wf[cb][ks * 4 + 0], acc0, 0, 0, 0);
                acc0 = __builtin_amdgcn_mfma_f32_16x16x32_f16(ah, wf[cb][ks * 4 + 2], acc0, 0, 0, 0);
                acc0 = __builtin_amdgcn_mfma_f32_16x16x32_f16(al, wf[cb][ks * 4 + 0], acc0, 0, 0, 0);
                acc1 = __builtin_amdgcn_mfma_f32_16x16x32_f16(ah, wf[cb][ks * 4 + 1], acc1, 0, 0, 0);
                acc1 = __builtin_amdgcn_mfma_f32_16x16x32_f16(ah, wf[cb][ks * 4 + 3], acc1, 0, 0, 0);
                acc1 = __builtin_amdgcn_mfma_f32_16x16x32_f16(al, wf[cb][ks * 4 + 1], acc1, 0, 0, 0);
            }
            if (t < 7) {
                #pragma unroll
                for (int i = 0; i < 4; ++i)
                    *(float4*)(&xl[(cb ^ 1) * 1088 + (srow + 4 * i) * 68 + scol]) = sreg[i];
                if (t < 6) {
                    int off = (t + 2) * 64;
                    #pragma unroll
                    for (int i = 0; i < 4; ++i)
                        sreg[i] = *(const float4*)(xgbase + (size_t)(srow + 4 * i) * PIX_ + off + scol);
                    #pragma unroll
                    for (int ks = 0; ks < 2; ++ks)
                        #pragma unroll
                        for (int s = 0; s < 4; ++s)
                            wf[cb][ks * 4 + s] = *(const half8*)(wbase + (size_t)(((t + 2) * 2 + ks) * 4 + s) * 512);
                }
            }
        }

        // epilogue: D layout (m89-verified): col = lane&15 (rho), row = kg*4 + reg (channel)
        __syncthreads();
        #pragma unroll
        for (int rr = 0; rr < 4; ++rr)
            smem[row16 * 64 + w * 16 + kg * 4 + rr] = acc0[rr];
        int rho1 = 16 + row16;
        if (rho1 < RHO_) {
            #pragma unroll
            for (int rr = 0; rr < 4; ++rr)
                smem[rho1 * 64 + w * 16 + kg * 4 + rr] = acc1[rr];
        }
        __syncthreads();
        for (int oi = tid; oi < 1600; oi += 256) {
            int rr = oi >> 6, cc = oi & 63;
            atomicAdd(&fe[((size_t)(rr * B_ + b)) * D_ + 384 + ct * 64 + cc], smem[oi]);
        }
    } else {
        // -------- polar role: width-mean, grid-stride ILP-4 --------
        int pid = (g * 4 + (r - 3)) * 8 + sub;           // 0..2047
        int wid = pid * 4 + w;
        for (int r0 = wid; r0 < NROWS; r0 += 4 * PNW) {
            float s[4];
            #pragma unroll
            for (int k = 0; k < 4; ++k) {
                int rr = r0 + k * PNW;
                float4 v = (rr < NROWS) ? ((const float4*)(polar + (size_t)rr * WP_))[lane]
                                        : make_float4(0.f, 0.f, 0.f, 0.f);
                s[k] = v.x + v.y + v.z + v.w;
            }
            #pragma unroll
            for (int m = 32; m >= 1; m >>= 1) {
                #pragma unroll
                for (int k = 0; k < 4; ++k) s[k] += __shfl_xor(s[k], m, 64);
            }
            if (lane == 0) {
                #pragma unroll
                for (int k = 0; k < 4; ++k) {
                    int rr = r0 + k * PNW;
                    if (rr < NROWS) {
                        int rho = rr % RHO_, cch = (rr / RHO_) % C_, bb = rr / (RHO_ * C_);
                        fe[((size_t)(rho * B_ + bb)) * D_ + cch] = s[k] * (1.f / 256.f);
                    }
                }
            }
        }
    }
}

// ---------------- K3: G[i][b][j] = fe[i][b][:] @ W1 + b1 ; wave per (i,b,j-half) ----------------
__global__ __launch_bounds__(256) void mlp_pre_kernel(const float* __restrict__ fe,
        const float* __restrict__ W1T, const float* __restrict__ b1_0,
        const float* __restrict__ b1s, float* __restrict__ G) {
    int lane = threadIdx.x & 63;
    int trip = blockIdx.x * 4 + (threadIdx.x >> 6);      // 0..1599 = (i,b,jh)
    int jh = trip & 1;
    int pair = trip >> 1;
    int i = pair >> 5, b = pair & 31;
    const float4* f4p = (const float4*)(fe + (size_t)(i * B_ + b) * D_);
    float4 f0 = f4p[lane], f1 = f4p[lane + 64], f2 = f4p[lane + 128];
    int j0 = jh * 20;
    #pragma unroll 2
    for (int j = j0; j < j0 + 20; ++j) {
        const float4* w4p = (const float4*)(W1T + ((size_t)i * HID_ + j) * D_);
        float4 w0 = w4p[lane], w1 = w4p[lane + 64], w2 = w4p[lane + 128];
        float s = f0.x*w0.x + f0.y*w0.y + f0.z*w0.z + f0.w*w0.w
                + f1.x*w1.x + f1.y*w1.y + f1.z*w1.z + f1.w*w1.w
                + f2.x*w2.x + f2.y*w2.y + f2.z*w2.z + f2.w*w2.w;
        #pragma unroll
        for (int m = 32; m >= 1; m >>= 1) s += __shfl_xor(s, m, 64);
        if (lane == 0) {
            float bias = (i == 0) ? b1_0[j] : b1s[(i - 1) * HID_ + j];
            G[(size_t)(i * B_ + b) * HID_ + j] = s + bias;
        }
    }
}

// ---------------- K4: sequential heads, register-resident, wave-synchronous ----------------
__global__ __launch_bounds__(64) void mlp_seq_kernel(const float* __restrict__ G,
        const float* __restrict__ W1s, const float* __restrict__ W2_0,
        const float* __restrict__ b2_0, const float* __restrict__ W2s,
        const float* __restrict__ b2s, float* __restrict__ out) {
    int lane = threadIdx.x;
    int j2 = lane & 31, b = blockIdx.x * 2 + (lane >> 5);
    bool hi = (j2 < 8);
    float g1[25], g2[25], wl1[25], wl2[25], w2a[25], w2b[25], bsc[25];
    #pragma unroll
    for (int i = 0; i < 25; ++i) {
        g1[i] = G[(size_t)(i * B_ + b) * HID_ + j2];
        g2[i] = hi ? G[(size_t)(i * B_ + b) * HID_ + 32 + j2] : 0.f;
    }
    wl1[0] = 0.f; wl2[0] = 0.f;
    w2a[0] = W2_0[j2]; w2b[0] = hi ? W2_0[32 + j2] : 0.f; bsc[0] = b2_0[0];
    #pragma unroll
    for (int i = 1; i < 25; ++i) {
        size_t base = ((size_t)(i - 1) * 769 + 768) * HID_;   // recurrent row of W1
        wl1[i] = W1s[base + j2];
        wl2[i] = hi ? W1s[base + 32 + j2] : 0.f;
        w2a[i] = W2s[(i - 1) * HID_ + j2];
        w2b[i] = hi ? W2s[(i - 1) * HID_ + 32 + j2] : 0.f;
        bsc[i] = b2s[i - 1];
    }
    float op = 0.f;
    #pragma unroll
    for (int i = 0; i < 25; ++i) {
        float x1 = g1[i] + op * wl1[i];
        float x2 = g2[i] + op * wl2[i];
        float p = gelu_exact(x1) * w2a[i] + gelu_exact(x2) * w2b[i];
        #pragma unroll
        for (int m = 16; m >= 1; m >>= 1) p += __shfl_xor(p, m, 64);   // stays within 32-lane group
        float o = p + bsc[i];
        op = o;
        if (j2 == 0) out[b * 25 + i] = fminf(fmaxf(o, 0.f), 3.14159265358979323846f);
    }
}

extern "C" void kernel_launch(void* const* d_in, const int* in_sizes, int n_in,
                              void* d_out, int out_size, void* d_ws, size_t ws_size,
                              hipStream_t stream) {
    const float* polar = (const float*)d_in[0];
    const float* cart  = (const float*)d_in[1];
    const float* grid  = (const float*)d_in[2];
    const float* W1_0  = (const float*)d_in[3];
    const float* b1_0  = (const float*)d_in[4];
    const float* W2_0  = (const float*)d_in[5];
    const float* b2_0  = (const float*)d_in[6];
    const float* W1s   = (const float*)d_in[7];
    const float* b1s   = (const float*)d_in[8];
    const float* W2s   = (const float*)d_in[9];
    const float* b2s   = (const float*)d_in[10];
    float* out = (float*)d_out;

    // ws layout: Wfrag[32 x 262144 halves = 16.8MB] | fe[f32] | G | W1T
    half_t* Wfrag = (half_t*)d_ws;
    float* fe   = (float*)(Wfrag + (size_t)B_ * WFRAG_B);
    float* G    = fe + (size_t)FE_N;
    float* W1T  = G + (size_t)RHO_ * B_ * HID_;

    prep_kernel<<<B_ * RHO_ + 25 + 50, 256, 0, stream>>>(grid, W1_0, W1s, Wfrag, W1T, fe);
    main_kernel<<<3584, 256, 0, stream>>>(polar, cart, Wfrag, fe);
    mlp_pre_kernel<<<(RHO_ * B_ * 2) / 4, 256, 0, stream>>>(fe, W1T, b1_0, b1s, G);
    mlp_seq_kernel<<<B_ / 2, 64, 0, stream>>>(G, W1s, W2_0, b2_0, W2s, b2s, out);
}

// Round 24
// 174.357 us; speedup vs baseline: 1.1090x; 1.1090x over previous
//
#include <hip/hip_runtime.h>
#include <math.h>

#define B_    32
#define C_    384
#define RHO_  25
#define WP_   256
#define PIX_  4096
#define D_    768
#define HID_  40
#define NROWS (B_*C_*RHO_)     // 307200
#define FE_N (RHO_*B_*D_)      // 614400
#define POLARBLK 2048
#define PCH 8                  // p-chunks of 512 for cart
#define WFRAG_B 262144         // per-b Wfrag halves: 128 tsteps x 4 slots x 64 lanes x 8

typedef _Float16 half_t;
typedef __attribute__((ext_vector_type(8))) _Float16 half8;
typedef __attribute__((ext_vector_type(4))) float f32x4;

__device__ __forceinline__ float gelu_exact(float x) {
    return 0.5f * x * (1.f + erff(x * 0.70710678118654752f));
}

// ---------------- K1: front — polar mean + bins(->MFMA-fragment-order f16 hi/lo) + W1T + fe-zero ----
__global__ __launch_bounds__(256) void front_kernel(const float* __restrict__ polar,
        const float* __restrict__ grid,
        const float* __restrict__ W1_0, const float* __restrict__ W1s,
        half_t* __restrict__ Wfrag, float* __restrict__ W1T, float* __restrict__ fe) {
    __shared__ float lb[PIX_];
    int tid = threadIdx.x;
    int bid = blockIdx.x;
    if (bid < POLARBLK) {
        // -------- polar role: wave per row, ILP-4 --------
        int wid = bid * 4 + (tid >> 6);
        int lane = tid & 63;
        const int NW = POLARBLK * 4;                     // 8192 waves
        for (int r0 = wid; r0 < NROWS; r0 += 4 * NW) {
            float s[4];
            #pragma unroll
            for (int k = 0; k < 4; ++k) {
                int r = r0 + k * NW;
                float4 v = (r < NROWS) ? ((const float4*)(polar + (size_t)r * WP_))[lane]
                                       : make_float4(0.f, 0.f, 0.f, 0.f);
                s[k] = v.x + v.y + v.z + v.w;
            }
            #pragma unroll
            for (int m = 32; m >= 1; m >>= 1) {
                #pragma unroll
                for (int k = 0; k < 4; ++k) s[k] += __shfl_xor(s[k], m, 64);
            }
            if (lane == 0) {
                #pragma unroll
                for (int k = 0; k < 4; ++k) {
                    int r = r0 + k * NW;
                    if (r < NROWS) {
                        int rho = r % RHO_, cch = (r / RHO_) % C_, bb = r / (RHO_ * C_);
                        fe[((size_t)(rho * B_ + bb)) * D_ + cch] = s[k] * (1.f / 256.f);
                    }
                }
            }
        }
    } else if (bid < POLARBLK + B_ * RHO_) {
        // -------- bins role: LDS scatter, then write f16 hi/lo in MFMA fragment order --------
        int bb = bid - POLARBLK;                         // 0..799
        for (int i = tid; i < PIX_ / 4; i += 256) ((float4*)lb)[i] = make_float4(0.f, 0.f, 0.f, 0.f);
        __syncthreads();
        int pt = bb * WP_ + tid;
        float2 g = ((const float2*)grid)[pt];
        float ix = (g.x + 1.f) * 32.f - 0.5f;
        float iy = (g.y + 1.f) * 32.f - 0.5f;
        float x0f = floorf(ix), y0f = floorf(iy);
        float fx = ix - x0f, fy = iy - y0f;
        int x0 = (int)x0f, y0 = (int)y0f;
        const float s = 1.f / 256.f;
        if ((unsigned)x0 < 64u) {
            if ((unsigned)y0 < 64u)       atomicAdd(&lb[y0 * 64 + x0],       (1.f - fx) * (1.f - fy) * s);
            if ((unsigned)(y0 + 1) < 64u) atomicAdd(&lb[(y0 + 1) * 64 + x0], (1.f - fx) * fy * s);
        }
        if ((unsigned)(x0 + 1) < 64u) {
            if ((unsigned)y0 < 64u)       atomicAdd(&lb[y0 * 64 + x0 + 1],       fx * (1.f - fy) * s);
            if ((unsigned)(y0 + 1) < 64u) atomicAdd(&lb[(y0 + 1) * 64 + x0 + 1], fx * fy * s);
        }
        __syncthreads();
        int b = bb / RHO_, rho = bb % RHO_;
        int slot_h = (rho < 16) ? 0 : 1;                 // hi slot; lo slot = slot_h + 2
        int r16 = rho & 15;
        half_t* base = Wfrag + (size_t)b * WFRAG_B;
        for (int i = tid; i < PIX_; i += 256) {
            int t = i >> 5, k = i & 31;
            int kg = k >> 3, ii = k & 7;
            float wv = lb[i];
            half_t h = (half_t)wv;
            size_t idx = ((size_t)(t * 4 + slot_h) * 64 + kg * 16 + r16) * 8 + ii;
            base[idx] = h;                               // hi
            base[idx + 1024] = (half_t)(wv - (float)h);  // lo (slot_h+2 -> +2*512 halves)
        }
    } else if (bid < POLARBLK + B_ * RHO_ + 25) {
        // -------- W1T role --------
        int i = bid - (POLARBLK + B_ * RHO_);            // head 0..24
        const float* src = (i == 0) ? W1_0 : (W1s + (size_t)(i - 1) * 769 * HID_);
        float* dst = W1T + (size_t)i * HID_ * D_;
        for (int idx = tid; idx < HID_ * D_; idx += 256) {
            int j = idx / D_, c = idx % D_;
            dst[idx] = src[c * HID_ + j];
        }
    } else {
        // -------- fe-zero role: cart half only, 16 rows per block --------
        int z = bid - (POLARBLK + B_ * RHO_ + 25);       // 0..49
        for (int i = tid; i < 16 * 96; i += 256) {       // 16 rows x 96 float4
            int row = z * 16 + (i / 96), e = i % 96;
            ((float4*)fe)[(size_t)row * 192 + 96 + e] = make_float4(0.f, 0.f, 0.f, 0.f);
        }
    }
}

// ---------------- K2: cart GEMM via MFMA, LDS X tiles + fragment-order W (all coalesced) ------
// Block = (b, 64-ch, 512-p); 1536 blocks, 4 waves. X staged per-wave into [16][68] LDS
// (2 bufs, coalesced 256B segments); W fragments read at base+lane*8 -> 1KB contiguous
// per instruction. Wave-synchronous main loop, no block barriers until epilogue.
__global__ __launch_bounds__(256) void cart_mfma_kernel(const float* __restrict__ cart,
        const half_t* __restrict__ Wfrag, float* __restrict__ fe) {
    __shared__ float smem[8704];                         // 4 waves x 2 bufs x [16][68]
    int tid = threadIdx.x;
    int bid = blockIdx.x;                                // 0..1535
    int b  = bid / (6 * PCH);
    int ct = (bid / PCH) % 6;
    int pc = bid % PCH;
    int w = tid >> 6, lane = tid & 63;
    int row16 = lane & 15, kg = lane >> 4;               // kg = k-group 0..3

    const float* xgbase = cart + ((size_t)b * C_ + ct * 64 + w * 16) * PIX_ + pc * 512;
    const half_t* wbase = Wfrag + (size_t)b * WFRAG_B + (size_t)(pc * 16) * 2048 + lane * 8;

    float* xl = smem + w * 2176;                         // this wave's two buffers
    int srow = lane >> 4;                                // staging row group 0..3
    int scol = (lane & 15) * 4;                          // staging col (floats)

    f32x4 acc0 = {0.f, 0.f, 0.f, 0.f};
    f32x4 acc1 = {0.f, 0.f, 0.f, 0.f};
    float4 sreg[4];
    half8 wf[2][8];

    // prologue: X tile0 -> regs -> LDS buf0; W tiles 0,1 -> wf; X tile1 -> regs
    #pragma unroll
    for (int i = 0; i < 4; ++i)
        sreg[i] = *(const float4*)(xgbase + (size_t)(srow + 4 * i) * PIX_ + scol);
    #pragma unroll
    for (int ks = 0; ks < 2; ++ks)
        #pragma unroll
        for (int s = 0; s < 4; ++s)
            wf[0][ks * 4 + s] = *(const half8*)(wbase + (size_t)(ks * 4 + s) * 512);
    #pragma unroll
    for (int i = 0; i < 4; ++i)
        *(float4*)(&xl[(srow + 4 * i) * 68 + scol]) = sreg[i];
    #pragma unroll
    for (int i = 0; i < 4; ++i)
        sreg[i] = *(const float4*)(xgbase + (size_t)(srow + 4 * i) * PIX_ + 64 + scol);
    #pragma unroll
    for (int ks = 0; ks < 2; ++ks)
        #pragma unroll
        for (int s = 0; s < 4; ++s)
            wf[1][ks * 4 + s] = *(const half8*)(wbase + (size_t)((2 + ks) * 4 + s) * 512);

    #pragma unroll
    for (int t = 0; t < 8; ++t) {                        // fully unrolled: all indices static
        const int cb = t & 1;
        const float* xb = xl + cb * 1088;
        #pragma unroll
        for (int ks = 0; ks < 2; ++ks) {
            float4 xa = *(const float4*)(xb + row16 * 68 + ks * 32 + kg * 8);
            float4 xc = *(const float4*)(xb + row16 * 68 + ks * 32 + kg * 8 + 4);
            float xs[8] = {xa.x, xa.y, xa.z, xa.w, xc.x, xc.y, xc.z, xc.w};
            half8 ah, al;
            #pragma unroll
            for (int i = 0; i < 8; ++i) {
                half_t h = (half_t)xs[i];
                ah[i] = h;
                al[i] = (half_t)(xs[i] - (float)h);
            }
            acc0 = __builtin_amdgcn_mfma_f32_16x16x32_f16(ah, wf[cb][ks * 4 + 0], acc0, 0, 0, 0);
            acc0 = __builtin_amdgcn_mfma_f32_16x16x32_f16(ah, wf[cb][ks * 4 + 2], acc0, 0, 0, 0);
            acc0 = __builtin_amdgcn_mfma_f32_16x16x32_f16(al, wf[cb][ks * 4 + 0], acc0, 0, 0, 0);
            acc1 = __builtin_amdgcn_mfma_f32_16x16x32_f16(ah, wf[cb][ks * 4 + 1], acc1, 0, 0, 0);
            acc1 = __builtin_amdgcn_mfma_f32_16x16x32_f16(ah, wf[cb][ks * 4 + 3], acc1, 0, 0, 0);
            acc1 = __builtin_amdgcn_mfma_f32_16x16x32_f16(al, wf[cb][ks * 4 + 1], acc1, 0, 0, 0);
        }
        if (t < 7) {
            // write staged X tile t+1 into the freed buffer (wave-synchronous)
            #pragma unroll
            for (int i = 0; i < 4; ++i)
                *(float4*)(&xl[(cb ^ 1) * 1088 + (srow + 4 * i) * 68 + scol]) = sreg[i];
            if (t < 6) {                                 // issue loads for tile t+2
                int off = (t + 2) * 64;
                #pragma unroll
                for (int i = 0; i < 4; ++i)
                    sreg[i] = *(const float4*)(xgbase + (size_t)(srow + 4 * i) * PIX_ + off + scol);
                #pragma unroll
                for (int ks = 0; ks < 2; ++ks)
                    #pragma unroll
                    for (int s = 0; s < 4; ++s)
                        wf[cb][ks * 4 + s] = *(const half8*)(wbase + (size_t)(((t + 2) * 2 + ks) * 4 + s) * 512);
            }
        }
    }

    // epilogue: D layout (m89-verified): col = lane&15 (rho), row = kg*4 + reg (channel)
    __syncthreads();                                     // staging done everywhere; reuse smem
    #pragma unroll
    for (int r = 0; r < 4; ++r)
        smem[row16 * 64 + w * 16 + kg * 4 + r] = acc0[r];
    int rho1 = 16 + row16;
    if (rho1 < RHO_) {
        #pragma unroll
        for (int r = 0; r < 4; ++r)
            smem[rho1 * 64 + w * 16 + kg * 4 + r] = acc1[r];
    }
    __syncthreads();
    for (int oi = tid; oi < 1600; oi += 256) {           // coalesced atomic adds
        int r = oi >> 6, cc = oi & 63;
        atomicAdd(&fe[((size_t)(r * B_ + b)) * D_ + 384 + ct * 64 + cc], smem[oi]);
    }
}

// ---------------- K3: G[i][b][j] = fe[i][b][:] @ W1 + b1 ; wave per (i,b,j-half) ----------------
__global__ __launch_bounds__(256) void mlp_pre_kernel(const float* __restrict__ fe,
        const float* __restrict__ W1T, const float* __restrict__ b1_0,
        const float* __restrict__ b1s, float* __restrict__ G) {
    int lane = threadIdx.x & 63;
    int trip = blockIdx.x * 4 + (threadIdx.x >> 6);      // 0..1599 = (i,b,jh)
    int jh = trip & 1;
    int pair = trip >> 1;
    int i = pair >> 5, b = pair & 31;
    const float4* f4p = (const float4*)(fe + (size_t)(i * B_ + b) * D_);
    float4 f0 = f4p[lane], f1 = f4p[lane + 64], f2 = f4p[lane + 128];
    int j0 = jh * 20;
    #pragma unroll 2
    for (int j = j0; j < j0 + 20; ++j) {
        const float4* w4p = (const float4*)(W1T + ((size_t)i * HID_ + j) * D_);
        float4 w0 = w4p[lane], w1 = w4p[lane + 64], w2 = w4p[lane + 128];
        float s = f0.x*w0.x + f0.y*w0.y + f0.z*w0.z + f0.w*w0.w
                + f1.x*w1.x + f1.y*w1.y + f1.z*w1.z + f1.w*w1.w
                + f2.x*w2.x + f2.y*w2.y + f2.z*w2.z + f2.w*w2.w;
        #pragma unroll
        for (int m = 32; m >= 1; m >>= 1) s += __shfl_xor(s, m, 64);
        if (lane == 0) {
            float bias = (i == 0) ? b1_0[j] : b1s[(i - 1) * HID_ + j];
            G[(size_t)(i * B_ + b) * HID_ + j] = s + bias;
        }
    }
}

// ---------------- K4: sequential heads, register-resident, wave-synchronous ----------------
__global__ __launch_bounds__(64) void mlp_seq_kernel(const float* __restrict__ G,
        const float* __restrict__ W1s, const float* __restrict__ W2_0,
        const float* __restrict__ b2_0, const float* __restrict__ W2s,
        const float* __restrict__ b2s, float* __restrict__ out) {
    int lane = threadIdx.x;
    int j2 = lane & 31, b = blockIdx.x * 2 + (lane >> 5);
    bool hi = (j2 < 8);
    float g1[25], g2[25], wl1[25], wl2[25], w2a[25], w2b[25], bsc[25];
    #pragma unroll
    for (int i = 0; i < 25; ++i) {
        g1[i] = G[(size_t)(i * B_ + b) * HID_ + j2];
        g2[i] = hi ? G[(size_t)(i * B_ + b) * HID_ + 32 + j2] : 0.f;
    }
    wl1[0] = 0.f; wl2[0] = 0.f;
    w2a[0] = W2_0[j2]; w2b[0] = hi ? W2_0[32 + j2] : 0.f; bsc[0] = b2_0[0];
    #pragma unroll
    for (int i = 1; i < 25; ++i) {
        size_t base = ((size_t)(i - 1) * 769 + 768) * HID_;   // recurrent row of W1
        wl1[i] = W1s[base + j2];
        wl2[i] = hi ? W1s[base + 32 + j2] : 0.f;
        w2a[i] = W2s[(i - 1) * HID_ + j2];
        w2b[i] = hi ? W2s[(i - 1) * HID_ + 32 + j2] : 0.f;
        bsc[i] = b2s[i - 1];
    }
    float op = 0.f;
    #pragma unroll
    for (int i = 0; i < 25; ++i) {
        float x1 = g1[i] + op * wl1[i];
        float x2 = g2[i] + op * wl2[i];
        float p = gelu_exact(x1) * w2a[i] + gelu_exact(x2) * w2b[i];
        #pragma unroll
        for (int m = 16; m >= 1; m >>= 1) p += __shfl_xor(p, m, 64);   // stays within 32-lane group
        float o = p + bsc[i];
        op = o;
        if (j2 == 0) out[b * 25 + i] = fminf(fmaxf(o, 0.f), 3.14159265358979323846f);
    }
}

extern "C" void kernel_launch(void* const* d_in, const int* in_sizes, int n_in,
                              void* d_out, int out_size, void* d_ws, size_t ws_size,
                              hipStream_t stream) {
    const float* polar = (const float*)d_in[0];
    const float* cart  = (const float*)d_in[1];
    const float* grid  = (const float*)d_in[2];
    const float* W1_0  = (const float*)d_in[3];
    const float* b1_0  = (const float*)d_in[4];
    const float* W2_0  = (const float*)d_in[5];
    const float* b2_0  = (const float*)d_in[6];
    const float* W1s   = (const float*)d_in[7];
    const float* b1s   = (const float*)d_in[8];
    const float* W2s   = (const float*)d_in[9];
    const float* b2s   = (const float*)d_in[10];
    float* out = (float*)d_out;

    // ws layout: Wfrag[32 x 262144 halves = 16.8MB] | fe[f32] | G | W1T
    half_t* Wfrag = (half_t*)d_ws;
    float* fe   = (float*)(Wfrag + (size_t)B_ * WFRAG_B);
    float* G    = fe + (size_t)FE_N;
    float* W1T  = G + (size_t)RHO_ * B_ * HID_;

    front_kernel<<<POLARBLK + B_ * RHO_ + 25 + 50, 256, 0, stream>>>(polar, grid, W1_0, W1s, Wfrag, W1T, fe);
    cart_mfma_kernel<<<B_ * 6 * PCH, 256, 0, stream>>>(cart, Wfrag, fe);
    mlp_pre_kernel<<<(RHO_ * B_ * 2) / 4, 256, 0, stream>>>(fe, W1T, b1_0, b1s, G);
    mlp_seq_kernel<<<B_ / 2, 64, 0, stream>>>(G, W1s, W2_0, b2_0, W2s, b2s, out);
}

// Round 25
// 173.593 us; speedup vs baseline: 1.1139x; 1.0044x over previous
//
#include <hip/hip_runtime.h>
#include <math.h>

#define B_    32
#define C_    384
#define RHO_  25
#define WP_   256
#define PIX_  4096
#define D_    768
#define HID_  40
#define NROWS (B_*C_*RHO_)     // 307200
#define FE_N (RHO_*B_*D_)      // 614400
#define POLARBLK 2048
#define PCH 8                  // p-chunks of 512 for cart
#define WFRAG_B 262144         // per-b Wfrag halves: 128 tsteps x 4 slots x 64 lanes x 8

typedef _Float16 half_t;
typedef __attribute__((ext_vector_type(8))) _Float16 half8;
typedef __attribute__((ext_vector_type(4))) float f32x4;

__device__ __forceinline__ float gelu_exact(float x) {
    return 0.5f * x * (1.f + erff(x * 0.70710678118654752f));
}

// ---------------- K1: front — polar mean + bins(->MFMA-fragment-order f16 hi/lo) + W1T + fe-zero ----
__global__ __launch_bounds__(256) void front_kernel(const float* __restrict__ polar,
        const float* __restrict__ grid,
        const float* __restrict__ W1_0, const float* __restrict__ W1s,
        half_t* __restrict__ Wfrag, float* __restrict__ W1T, float* __restrict__ fe) {
    __shared__ float lb[PIX_];
    int tid = threadIdx.x;
    int bid = blockIdx.x;
    if (bid < POLARBLK) {
        // -------- polar role: wave per row, ILP-4 --------
        int wid = bid * 4 + (tid >> 6);
        int lane = tid & 63;
        const int NW = POLARBLK * 4;                     // 8192 waves
        for (int r0 = wid; r0 < NROWS; r0 += 4 * NW) {
            float s[4];
            #pragma unroll
            for (int k = 0; k < 4; ++k) {
                int r = r0 + k * NW;
                float4 v = (r < NROWS) ? ((const float4*)(polar + (size_t)r * WP_))[lane]
                                       : make_float4(0.f, 0.f, 0.f, 0.f);
                s[k] = v.x + v.y + v.z + v.w;
            }
            #pragma unroll
            for (int m = 32; m >= 1; m >>= 1) {
                #pragma unroll
                for (int k = 0; k < 4; ++k) s[k] += __shfl_xor(s[k], m, 64);
            }
            if (lane == 0) {
                #pragma unroll
                for (int k = 0; k < 4; ++k) {
                    int r = r0 + k * NW;
                    if (r < NROWS) {
                        int rho = r % RHO_, cch = (r / RHO_) % C_, bb = r / (RHO_ * C_);
                        fe[((size_t)(rho * B_ + bb)) * D_ + cch] = s[k] * (1.f / 256.f);
                    }
                }
            }
        }
    } else if (bid < POLARBLK + B_ * RHO_) {
        // -------- bins role: LDS scatter, then write f16 hi/lo in MFMA fragment order --------
        int bb = bid - POLARBLK;                         // 0..799
        for (int i = tid; i < PIX_ / 4; i += 256) ((float4*)lb)[i] = make_float4(0.f, 0.f, 0.f, 0.f);
        __syncthreads();
        int pt = bb * WP_ + tid;
        float2 g = ((const float2*)grid)[pt];
        float ix = (g.x + 1.f) * 32.f - 0.5f;
        float iy = (g.y + 1.f) * 32.f - 0.5f;
        float x0f = floorf(ix), y0f = floorf(iy);
        float fx = ix - x0f, fy = iy - y0f;
        int x0 = (int)x0f, y0 = (int)y0f;
        const float s = 1.f / 256.f;
        if ((unsigned)x0 < 64u) {
            if ((unsigned)y0 < 64u)       atomicAdd(&lb[y0 * 64 + x0],       (1.f - fx) * (1.f - fy) * s);
            if ((unsigned)(y0 + 1) < 64u) atomicAdd(&lb[(y0 + 1) * 64 + x0], (1.f - fx) * fy * s);
        }
        if ((unsigned)(x0 + 1) < 64u) {
            if ((unsigned)y0 < 64u)       atomicAdd(&lb[y0 * 64 + x0 + 1],       fx * (1.f - fy) * s);
            if ((unsigned)(y0 + 1) < 64u) atomicAdd(&lb[(y0 + 1) * 64 + x0 + 1], fx * fy * s);
        }
        __syncthreads();
        int b = bb / RHO_, rho = bb % RHO_;
        int slot_h = (rho < 16) ? 0 : 1;                 // hi slot; lo slot = slot_h + 2
        int r16 = rho & 15;
        half_t* base = Wfrag + (size_t)b * WFRAG_B;
        for (int i = tid; i < PIX_; i += 256) {
            int t = i >> 5, k = i & 31;
            int kg = k >> 3, ii = k & 7;
            float wv = lb[i];
            half_t h = (half_t)wv;
            size_t idx = ((size_t)(t * 4 + slot_h) * 64 + kg * 16 + r16) * 8 + ii;
            base[idx] = h;                               // hi
            base[idx + 1024] = (half_t)(wv - (float)h);  // lo (slot_h+2 -> +2*512 halves)
        }
    } else if (bid < POLARBLK + B_ * RHO_ + 25) {
        // -------- W1T role --------
        int i = bid - (POLARBLK + B_ * RHO_);            // head 0..24
        const float* src = (i == 0) ? W1_0 : (W1s + (size_t)(i - 1) * 769 * HID_);
        float* dst = W1T + (size_t)i * HID_ * D_;
        for (int idx = tid; idx < HID_ * D_; idx += 256) {
            int j = idx / D_, c = idx % D_;
            dst[idx] = src[c * HID_ + j];
        }
    } else {
        // -------- fe-zero role: cart half only, 16 rows per block --------
        int z = bid - (POLARBLK + B_ * RHO_ + 25);       // 0..49
        for (int i = tid; i < 16 * 96; i += 256) {       // 16 rows x 96 float4
            int row = z * 16 + (i / 96), e = i % 96;
            ((float4*)fe)[(size_t)row * 192 + 96 + e] = make_float4(0.f, 0.f, 0.f, 0.f);
        }
    }
}

// ---------------- K2: cart GEMM via MFMA — 3-tile X lookahead (2 sreg sets), coalesced ----------
// Block = (b, 64-ch, 512-p); 1536 blocks, 4 waves. X staged per-wave into [16][68] LDS
// (2 bufs); tile k loads into sreg[k&1]; iter t writes tile t+1 to LDS then reloads that
// set with tile t+3 -> load->LDS-write distance = 2 compute phases (~900 cy, covers HBM).
// W fragments at base+lane*8 (1KB contiguous), 2-deep reg ping-pong (L2-covered).
// Wave-synchronous main loop, no block barriers until epilogue.
__global__ __launch_bounds__(256) void cart_mfma_kernel(const float* __restrict__ cart,
        const half_t* __restrict__ Wfrag, float* __restrict__ fe) {
    __shared__ float smem[8704];                         // 4 waves x 2 bufs x [16][68]
    int tid = threadIdx.x;
    int bid = blockIdx.x;                                // 0..1535
    int b  = bid / (6 * PCH);
    int ct = (bid / PCH) % 6;
    int pc = bid % PCH;
    int w = tid >> 6, lane = tid & 63;
    int row16 = lane & 15, kg = lane >> 4;               // kg = k-group 0..3

    const float* xgbase = cart + ((size_t)b * C_ + ct * 64 + w * 16) * PIX_ + pc * 512;
    const half_t* wbase = Wfrag + (size_t)b * WFRAG_B + (size_t)(pc * 16) * 2048 + lane * 8;

    float* xl = smem + w * 2176;                         // this wave's two buffers
    int srow = lane >> 4;                                // staging row group 0..3
    int scol = (lane & 15) * 4;                          // staging col (floats)

    f32x4 acc0 = {0.f, 0.f, 0.f, 0.f};
    f32x4 acc1 = {0.f, 0.f, 0.f, 0.f};
    float4 sreg[2][4];                                   // 2 staging sets: tile k in sreg[k&1]
    half8 wf[2][8];

    // prologue: tile0 -> sreg0 -> LDS buf0; then tile1 -> sreg1, tile2 -> sreg0 (in flight);
    // W tiles 0,1 -> wf.
    #pragma unroll
    for (int i = 0; i < 4; ++i)
        sreg[0][i] = *(const float4*)(xgbase + (size_t)(srow + 4 * i) * PIX_ + scol);
    #pragma unroll
    for (int ks = 0; ks < 2; ++ks)
        #pragma unroll
        for (int s = 0; s < 4; ++s)
            wf[0][ks * 4 + s] = *(const half8*)(wbase + (size_t)(ks * 4 + s) * 512);
    #pragma unroll
    for (int i = 0; i < 4; ++i)
        *(float4*)(&xl[(srow + 4 * i) * 68 + scol]) = sreg[0][i];
    #pragma unroll
    for (int i = 0; i < 4; ++i)
        sreg[1][i] = *(const float4*)(xgbase + (size_t)(srow + 4 * i) * PIX_ + 64 + scol);
    #pragma unroll
    for (int i = 0; i < 4; ++i)
        sreg[0][i] = *(const float4*)(xgbase + (size_t)(srow + 4 * i) * PIX_ + 128 + scol);
    #pragma unroll
    for (int ks = 0; ks < 2; ++ks)
        #pragma unroll
        for (int s = 0; s < 4; ++s)
            wf[1][ks * 4 + s] = *(const half8*)(wbase + (size_t)((2 + ks) * 4 + s) * 512);

    #pragma unroll
    for (int t = 0; t < 8; ++t) {                        // fully unrolled: all indices static
        const int cb = t & 1;
        const float* xb = xl + cb * 1088;
        #pragma unroll
        for (int ks = 0; ks < 2; ++ks) {
            float4 xa = *(const float4*)(xb + row16 * 68 + ks * 32 + kg * 8);
            float4 xc = *(const float4*)(xb + row16 * 68 + ks * 32 + kg * 8 + 4);
            float xs[8] = {xa.x, xa.y, xa.z, xa.w, xc.x, xc.y, xc.z, xc.w};
            half8 ah, al;
            #pragma unroll
            for (int i = 0; i < 8; ++i) {
                half_t h = (half_t)xs[i];
                ah[i] = h;
                al[i] = (half_t)(xs[i] - (float)h);
            }
            acc0 = __builtin_amdgcn_mfma_f32_16x16x32_f16(ah, wf[cb][ks * 4 + 0], acc0, 0, 0, 0);
            acc0 = __builtin_amdgcn_mfma_f32_16x16x32_f16(ah, wf[cb][ks * 4 + 2], acc0, 0, 0, 0);
            acc0 = __builtin_amdgcn_mfma_f32_16x16x32_f16(al, wf[cb][ks * 4 + 0], acc0, 0, 0, 0);
            acc1 = __builtin_amdgcn_mfma_f32_16x16x32_f16(ah, wf[cb][ks * 4 + 1], acc1, 0, 0, 0);
            acc1 = __builtin_amdgcn_mfma_f32_16x16x32_f16(ah, wf[cb][ks * 4 + 3], acc1, 0, 0, 0);
            acc1 = __builtin_amdgcn_mfma_f32_16x16x32_f16(al, wf[cb][ks * 4 + 1], acc1, 0, 0, 0);
        }
        if (t < 7) {
            const int ns = (t + 1) & 1;                  // set holding tile t+1
            // write staged X tile t+1 into the freed LDS buffer (wave-synchronous)
            #pragma unroll
            for (int i = 0; i < 4; ++i)
                *(float4*)(&xl[ns * 1088 + (srow + 4 * i) * 68 + scol]) = sreg[ns][i];
            if (t < 5) {                                 // reload freed set with tile t+3
                int off = (t + 3) * 64;
                #pragma unroll
                for (int i = 0; i < 4; ++i)
                    sreg[ns][i] = *(const float4*)(xgbase + (size_t)(srow + 4 * i) * PIX_ + off + scol);
            }
            if (t < 6) {                                 // W tile t+2 into wf[cb]
                #pragma unroll
                for (int ks = 0; ks < 2; ++ks)
                    #pragma unroll
                    for (int s = 0; s < 4; ++s)
                        wf[cb][ks * 4 + s] = *(const half8*)(wbase + (size_t)(((t + 2) * 2 + ks) * 4 + s) * 512);
            }
        }
    }

    // epilogue: D layout (m89-verified): col = lane&15 (rho), row = kg*4 + reg (channel)
    __syncthreads();                                     // staging done everywhere; reuse smem
    #pragma unroll
    for (int r = 0; r < 4; ++r)
        smem[row16 * 64 + w * 16 + kg * 4 + r] = acc0[r];
    int rho1 = 16 + row16;
    if (rho1 < RHO_) {
        #pragma unroll
        for (int r = 0; r < 4; ++r)
            smem[rho1 * 64 + w * 16 + kg * 4 + r] = acc1[r];
    }
    __syncthreads();
    for (int oi = tid; oi < 1600; oi += 256) {           // coalesced atomic adds
        int r = oi >> 6, cc = oi & 63;
        atomicAdd(&fe[((size_t)(r * B_ + b)) * D_ + 384 + ct * 64 + cc], smem[oi]);
    }
}

// ---------------- K3: G[i][b][j] = fe[i][b][:] @ W1 + b1 ; wave per (i,b,j-half) ----------------
__global__ __launch_bounds__(256) void mlp_pre_kernel(const float* __restrict__ fe,
        const float* __restrict__ W1T, const float* __restrict__ b1_0,
        const float* __restrict__ b1s, float* __restrict__ G) {
    int lane = threadIdx.x & 63;
    int trip = blockIdx.x * 4 + (threadIdx.x >> 6);      // 0..1599 = (i,b,jh)
    int jh = trip & 1;
    int pair = trip >> 1;
    int i = pair >> 5, b = pair & 31;
    const float4* f4p = (const float4*)(fe + (size_t)(i * B_ + b) * D_);
    float4 f0 = f4p[lane], f1 = f4p[lane + 64], f2 = f4p[lane + 128];
    int j0 = jh * 20;
    #pragma unroll 2
    for (int j = j0; j < j0 + 20; ++j) {
        const float4* w4p = (const float4*)(W1T + ((size_t)i * HID_ + j) * D_);
        float4 w0 = w4p[lane], w1 = w4p[lane + 64], w2 = w4p[lane + 128];
        float s = f0.x*w0.x + f0.y*w0.y + f0.z*w0.z + f0.w*w0.w
                + f1.x*w1.x + f1.y*w1.y + f1.z*w1.z + f1.w*w1.w
                + f2.x*w2.x + f2.y*w2.y + f2.z*w2.z + f2.w*w2.w;
        #pragma unroll
        for (int m = 32; m >= 1; m >>= 1) s += __shfl_xor(s, m, 64);
        if (lane == 0) {
            float bias = (i == 0) ? b1_0[j] : b1s[(i - 1) * HID_ + j];
            G[(size_t)(i * B_ + b) * HID_ + j] = s + bias;
        }
    }
}

// ---------------- K4: sequential heads, register-resident, wave-synchronous ----------------
__global__ __launch_bounds__(64) void mlp_seq_kernel(const float* __restrict__ G,
        const float* __restrict__ W1s, const float* __restrict__ W2_0,
        const float* __restrict__ b2_0, const float* __restrict__ W2s,
        const float* __restrict__ b2s, float* __restrict__ out) {
    int lane = threadIdx.x;
    int j2 = lane & 31, b = blockIdx.x * 2 + (lane >> 5);
    bool hi = (j2 < 8);
    float g1[25], g2[25], wl1[25], wl2[25], w2a[25], w2b[25], bsc[25];
    #pragma unroll
    for (int i = 0; i < 25; ++i) {
        g1[i] = G[(size_t)(i * B_ + b) * HID_ + j2];
        g2[i] = hi ? G[(size_t)(i * B_ + b) * HID_ + 32 + j2] : 0.f;
    }
    wl1[0] = 0.f; wl2[0] = 0.f;
    w2a[0] = W2_0[j2]; w2b[0] = hi ? W2_0[32 + j2] : 0.f; bsc[0] = b2_0[0];
    #pragma unroll
    for (int i = 1; i < 25; ++i) {
        size_t base = ((size_t)(i - 1) * 769 + 768) * HID_;   // recurrent row of W1
        wl1[i] = W1s[base + j2];
        wl2[i] = hi ? W1s[base + 32 + j2] : 0.f;
        w2a[i] = W2s[(i - 1) * HID_ + j2];
        w2b[i] = hi ? W2s[(i - 1) * HID_ + 32 + j2] : 0.f;
        bsc[i] = b2s[i - 1];
    }
    float op = 0.f;
    #pragma unroll
    for (int i = 0; i < 25; ++i) {
        float x1 = g1[i] + op * wl1[i];
        float x2 = g2[i] + op * wl2[i];
        float p = gelu_exact(x1) * w2a[i] + gelu_exact(x2) * w2b[i];
        #pragma unroll
        for (int m = 16; m >= 1; m >>= 1) p += __shfl_xor(p, m, 64);   // stays within 32-lane group
        float o = p + bsc[i];
        op = o;
        if (j2 == 0) out[b * 25 + i] = fminf(fmaxf(o, 0.f), 3.14159265358979323846f);
    }
}

extern "C" void kernel_launch(void* const* d_in, const int* in_sizes, int n_in,
                              void* d_out, int out_size, void* d_ws, size_t ws_size,
                              hipStream_t stream) {
    const float* polar = (const float*)d_in[0];
    const float* cart  = (const float*)d_in[1];
    const float* grid  = (const float*)d_in[2];
    const float* W1_0  = (const float*)d_in[3];
    const float* b1_0  = (const float*)d_in[4];
    const float* W2_0  = (const float*)d_in[5];
    const float* b2_0  = (const float*)d_in[6];
    const float* W1s   = (const float*)d_in[7];
    const float* b1s   = (const float*)d_in[8];
    const float* W2s   = (const float*)d_in[9];
    const float* b2s   = (const float*)d_in[10];
    float* out = (float*)d_out;

    // ws layout: Wfrag[32 x 262144 halves = 16.8MB] | fe[f32] | G | W1T
    half_t* Wfrag = (half_t*)d_ws;
    float* fe   = (float*)(Wfrag + (size_t)B_ * WFRAG_B);
    float* G    = fe + (size_t)FE_N;
    float* W1T  = G + (size_t)RHO_ * B_ * HID_;

    front_kernel<<<POLARBLK + B_ * RHO_ + 25 + 50, 256, 0, stream>>>(polar, grid, W1_0, W1s, Wfrag, W1T, fe);
    cart_mfma_kernel<<<B_ * 6 * PCH, 256, 0, stream>>>(cart, Wfrag, fe);
    mlp_pre_kernel<<<(RHO_ * B_ * 2) / 4, 256, 0, stream>>>(fe, W1T, b1_0, b1s, G);
    mlp_seq_kernel<<<B_ / 2, 64, 0, stream>>>(G, W1s, W2_0, b2_0, W2s, b2s, out);
}